// Round 5
// baseline (440.212 us; speedup 1.0000x reference)
//
#include <hip/hip_runtime.h>
#include <stdint.h>

#define EPSF 1e-5f

typedef __bf16 bf16;
typedef __attribute__((ext_vector_type(8))) __bf16 bf16x8;
typedef __attribute__((ext_vector_type(4))) float f32x4;

// async global->LDS, 16B per lane, dest = wave-uniform base + lane*16 (linear)
#define GL16(src, dst) __builtin_amdgcn_global_load_lds( \
    (const __attribute__((address_space(1))) void*)(src), \
    (__attribute__((address_space(3))) void*)(dst), 16, 0, 0)
// IR+ISA ordering fence for memory ops (pins GL16 issue order vs A-loads/ds_reads)
#define MEMFENCE() asm volatile("" ::: "memory")

// counted vmcnt: N = 2*MM keeps the 2-deep A-frag prefetch in flight while forcing
// all older ops (the GL16 staging DMAs, issued first) retired. Tight + sound.
template<int N> __device__ __forceinline__ void vwait() {
  static_assert(N == 2 || N == 4 || N == 6, "unsupported vmcnt");
  if constexpr (N == 2) asm volatile("s_waitcnt vmcnt(2)" ::: "memory");
  else if constexpr (N == 4) asm volatile("s_waitcnt vmcnt(4)" ::: "memory");
  else asm volatile("s_waitcnt vmcnt(6)" ::: "memory");
}

// ---------------- quantization + BN-fold + MFMA-fragment prepack -----------------
// Median via bitwise order-statistic binary search (MSB->LSB), packed 16|16 ranks.
struct QArgs {
  const float* w[5];
  const float* g[5];
  const float* bb[5];
  const float* m[5];
  const float* v[5];
  bf16* wpk[3];
  float* alpha[3];
  float* beta[3];
};

__global__ __launch_bounds__(256)
void quant_kernel(QArgs qa) {
  __shared__ int red[2][4];
  const int tid = threadIdx.x;
  const int blk = blockIdx.x;
  int layer, o;
  if (blk < 128)      { layer = 0; o = blk; }
  else if (blk < 192) { layer = 1; o = blk - 128; }
  else if (blk < 256) { layer = 2; o = blk - 192; }
  else if (blk < 320) { layer = 3; o = blk - 256; }
  else                { layer = 4; o = blk - 320; }
  const int I_[5]     = {256, 256, 64, 64, 64};
  const int gemm_[5]  = {0, 0, 1, 1, 2};
  const int obase_[5] = {0, 128, 0, 64, 0};
  const int gNMT[3]   = {12, 8, 4};
  const int I = I_[layer];
  const int n = I * 9;                       // 2304 or 576
  const float* w = qa.w[layer] + (size_t)o * n;

  unsigned key[9];
#pragma unroll
  for (int j = 0; j < 9; ++j) key[j] = 0xFFFFFFFFu;   // pad: never < cand
  {
    int c2 = 0;
    for (int i = tid; i < n; i += 256) key[c2++] = __float_as_uint(fabsf(w[i]));
  }

  const int wv = tid >> 6;
  unsigned pfx[2] = {0u, 0u};
  const int rank0 = n / 2 - 1, rank1 = n / 2;
  int pp = 0;
  for (int bit = 31; bit >= 0; --bit) {
    const unsigned c0 = pfx[0] | (1u << bit);
    const unsigned c1 = pfx[1] | (1u << bit);
    int loc = 0;
#pragma unroll
    for (int j = 0; j < 9; ++j)
      loc += (key[j] < c0 ? 1 : 0) + (key[j] < c1 ? 0x10000 : 0);
    loc += __shfl_xor(loc, 32); loc += __shfl_xor(loc, 16);
    loc += __shfl_xor(loc, 8);  loc += __shfl_xor(loc, 4);
    loc += __shfl_xor(loc, 2);  loc += __shfl_xor(loc, 1);
    if ((tid & 63) == 0) red[pp][wv] = loc;
    __syncthreads();
    const int tot = red[pp][0] + red[pp][1] + red[pp][2] + red[pp][3];
    if ((tot & 0xFFFF) <= rank0) pfx[0] = c0;
    if ((tot >> 16)    <= rank1) pfx[1] = c1;
    pp ^= 1;
  }
  const float s =
      fmaxf(0.5f * (__uint_as_float(pfx[0]) + __uint_as_float(pfx[1])), EPSF);

  const int g  = gemm_[layer];
  const int ob = obase_[layer];
  const int NMT = gNMT[g];
  if (tid == 0) {
    float inv = qa.g[layer][o] / sqrtf(qa.v[layer][o] + EPSF);
    qa.alpha[g][ob + o] = s * inv;
    qa.beta[g][ob + o]  = qa.bb[layer][o] - qa.m[layer][o] * inv;
  }
  const int og  = ob + o;
  const int mt  = og >> 4;
  const int l16 = og & 15;
  bf16* wp = qa.wpk[g];
  for (int i = tid; i < n; i += 256) {
    float t = rintf(w[i] / s);
    t = fmaxf(-1.f, fminf(1.f, t));
    int c = i / 9, pos = i % 9;
    int k = pos * I + c;
    int ks = k >> 5, kq = (k >> 3) & 3, jj = k & 7;
    wp[((size_t)((ks * NMT + mt) * 64 + kq * 16 + l16)) * 8 + jj] = (bf16)t;
  }
}

// ---------------- NCHW fp32 -> c-minor bf16 transpose: xT[b][h][w][256] ----------
// float4 global loads (4x fewer VMEM instrs), float2 LDS reads on output side.
__global__ __launch_bounds__(256)
void transpose_k(const float* __restrict__ x, bf16* __restrict__ xT,
                 float* __restrict__ zp) {
  if (blockIdx.x == 0 && threadIdx.x < 32) zp[threadIdx.x] = 0.0f;  // 128B zero page
  __shared__ float tile[64 * 66];
  const int tid = threadIdx.x;
  const int blk = blockIdx.x;
  const int cg = blk & 3;
  const int h  = (blk >> 2) & 63;
  const int b  = blk >> 8;
  const int w4 = (tid & 15) * 4;
  const int cb = tid >> 4;               // 0..15
#pragma unroll
  for (int p = 0; p < 4; ++p) {
    int c = cb + p * 16;
    const float4 v =
        *(const float4*)&x[(((size_t)(b * 256 + cg * 64 + c)) * 64 + h) * 64 + w4];
    tile[(w4 + 0) * 66 + c] = v.x;
    tile[(w4 + 1) * 66 + c] = v.y;
    tile[(w4 + 2) * 66 + c] = v.z;
    tile[(w4 + 3) * 66 + c] = v.w;
  }
  __syncthreads();
#pragma unroll
  for (int p = 0; p < 2; ++p) {
    int id = tid + p * 256;
    int c8 = id & 7, w2 = id >> 3;
    const float* src = &tile[w2 * 66 + c8 * 8];
    float2 f0 = *(const float2*)(src + 0);
    float2 f1 = *(const float2*)(src + 2);
    float2 f2 = *(const float2*)(src + 4);
    float2 f3 = *(const float2*)(src + 6);
    bf16x8 v;
    v[0] = (bf16)f0.x; v[1] = (bf16)f0.y; v[2] = (bf16)f1.x; v[3] = (bf16)f1.y;
    v[4] = (bf16)f2.x; v[5] = (bf16)f2.y; v[6] = (bf16)f3.x; v[7] = (bf16)f3.y;
    *(bf16x8*)&xT[(((size_t)(b * 64 + h)) * 64 + w2) * 256 + cg * 64 + c8 * 8] = v;
  }
}

// ---------------- implicit-GEMM conv3x3 (pad=1) + fused BN + SiLU ----------------
// 1024 thr = 16 waves. Block tile: 256 px (4 rows x 64 w) x NMT*16 ch.
// 4-row blocks halve weight(A) L2 bytes/FLOP (unique A per block per c-iter is
// fixed at 110KB; pixels doubled) and cut halo overfetch (6 staged rows per 4
// output rows vs 4 per 2). Per-wave tile unchanged: 1 row x 64 px x MM*16 ch ->
// VGPR budget identical, 4 waves/SIMD, 1 block/CU.
// Staging: global_load_lds width=16, linear LDS (2 x 1600 chunks = 51.2 KB),
// chunk XOR-swizzle on global source + read side (G21). Counted vmcnt(2*MM):
// GL16s retired, 2-deep A-frag ring in flight. Bijective XCD swizzle (512%8==0)
// groups 4 images per XCD for x/halo L2 locality.
template<int CIN, int NMT, int MM, int C1, bool HASPAD>
__global__ __launch_bounds__(1024, 4)
void conv_k(const bf16* __restrict__ xin,   // [B][64][64][CIN] c-minor bf16
            const bf16* __restrict__ wpk,
            const float* __restrict__ alpha,
            const float* __restrict__ beta,
            float* __restrict__ out, int chan_off,
            bf16* __restrict__ padout,      // [B][64][64][64] c-minor bf16
            const bf16* __restrict__ zpage) {
  constexpr int NC = CIN / 32;
  __shared__ __align__(16) union U {
    bf16 xs[2][12800];  // 2 x 1600 chunks x 16B = 51.2 KB (16 guard chunks/buf)
    bf16 ep[256 * 72];  // 36.9 KB epilogue transpose buffer
  } sm;

  const int tid  = threadIdx.x;
  const int wave = tid >> 6;             // 0..15
  const int lane = tid & 63;
  const int q    = lane >> 4;
  const int t16  = lane & 15;
  const int rw   = wave >> 2;            // output row within block (0..3)
  const int mt0  = (wave & 3) * MM;
  const int wg   = (int)blockIdx.x;
  const int wgid = (wg & 7) * 64 + (wg >> 3);   // XCD swizzle: 4 images per XCD
  const int b    = wgid >> 4;
  const int h0   = (wgid & 15) << 2;

  // staging: 1584 live chunks = 6 rows x 66 cols x 4 ch-chunks; slot id = chunk id
  const bf16* srcp[2];
  int step[2];
#pragma unroll
  for (int p = 0; p < 2; ++p) {
    const int id = tid + p * 1024;
    const int c8p = id & 3, rj = id >> 2;
    const int j = rj % 66, r = rj / 66;
    const int hh = h0 + r - 1, ww = j - 1;
    const bool v = (id < 1584) && ((unsigned)hh < 64u) && ((unsigned)ww < 64u);
    const int c8 = c8p ^ ((j >> 1) & 3);          // inverse swizzle on source
    srcp[p] = v ? &xin[(((size_t)(b * 64 + hh)) * 64 + ww) * CIN + c8 * 8] : zpage;
    step[p] = v ? 32 : 0;                          // +32 ch per c-iter, pad lanes pinned
  }

  // B-read base addresses (buf0), one per kw
  int Caddr[3];
#pragma unroll
  for (int kw = 0; kw < 3; ++kw) {
    const int col = t16 + kw;
    Caddr[kw] = rw * 4224 + col * 64 + ((q ^ ((col >> 1) & 3)) << 4);
  }

  char* const lds0 = (char*)&sm.xs[0][0];

  // prologue staging (p=1 covers ids 1024..1599: waves 0..8 only; wave 8 lanes
  // 48-63 are guard chunks fed from the zero page)
  GL16(srcp[0], lds0 + wave * 1024);
  if (wave < 9) GL16(srcp[1], lds0 + 16384 + wave * 1024);
  if constexpr (NC == 2) {               // stage second 32-ch chunk into buf1 now
    GL16(srcp[0] + step[0], lds0 + 25600 + wave * 1024);          // step: pad-safe
    if (wave < 9) GL16(srcp[1] + step[1], lds0 + 25600 + 16384 + wave * 1024);
  } else {
#pragma unroll
    for (int p = 0; p < 2; ++p) srcp[p] += step[p];
  }
  MEMFENCE();

  // A-fragment ring, 2 taps deep: fr[t%3] holds tap t
  bf16x8 fr[3][MM];
#pragma unroll
  for (int mm = 0; mm < MM; ++mm) {
    fr[0][mm] = *(const bf16x8*)&wpk[((size_t)(mt0 + mm) * 64 + lane) * 8];
    fr[1][mm] = *(const bf16x8*)&wpk[((size_t)(NC * NMT + mt0 + mm) * 64 + lane) * 8];
  }

  f32x4 acc[4][MM] = {};
  int tog = 25600;

  for (int ci = 0; ci < NC; ++ci) {
    if (NC > 2 || ci == 0) {
      vwait<2 * MM>();                   // GL16s retired; A-frag ring stays in flight
      __builtin_amdgcn_s_barrier();
    }
    if constexpr (NC > 2) {
      if (ci + 1 < NC) {                 // issue next chunk's direct-to-LDS loads now
        char* lb = lds0 + (((ci + 1) & 1) ? 25600 : 0);
        GL16(srcp[0], lb + wave * 1024);
        if (wave < 9) GL16(srcp[1], lb + 16384 + wave * 1024);
#pragma unroll
        for (int p = 0; p < 2; ++p) srcp[p] += step[p];
      }
    }
    MEMFENCE();                          // GL16 issue pinned before A-loads/ds_reads
    __builtin_amdgcn_s_setprio(1);
#pragma unroll
    for (int pos = 0; pos < 9; ++pos) {
      const int t = pos + 2;             // prefetch 2 taps ahead into fr[t%3]
      if (t <= 8) {
        const int ksn = t * NC + ci;
#pragma unroll
        for (int mm = 0; mm < MM; ++mm)
          fr[t % 3][mm] = *(const bf16x8*)&wpk[((size_t)(ksn * NMT + mt0 + mm) * 64 + lane) * 8];
      } else if (ci + 1 < NC) {          // next c-iter taps 0/1, fly across barrier
        const int ksn = (t - 9) * NC + (ci + 1);
#pragma unroll
        for (int mm = 0; mm < MM; ++mm)
          fr[t % 3][mm] = *(const bf16x8*)&wpk[((size_t)(ksn * NMT + mt0 + mm) * 64 + lane) * 8];
      }
      const int kh = pos / 3, kw = pos % 3;
#pragma unroll
      for (int nt = 0; nt < 4; ++nt) {
        const bf16x8 bv =
            *(const bf16x8*)(lds0 + (Caddr[kw] + nt * 1024 + kh * 4224));
#pragma unroll
        for (int mm = 0; mm < MM; ++mm)
          acc[nt][mm] = __builtin_amdgcn_mfma_f32_16x16x32_bf16(fr[pos % 3][mm], bv, acc[nt][mm], 0, 0, 0);
      }
    }
    __builtin_amdgcn_s_setprio(0);
#pragma unroll
    for (int kw = 0; kw < 3; ++kw) Caddr[kw] += tog;   // buffer toggle
    tog = -tog;
  }

  // epilogue: BN + SiLU; fp32 NCHW stores for o < C1
  const int h = h0 + rw;
#pragma unroll
  for (int mm = 0; mm < MM; ++mm) {
    const int o0 = (mt0 + mm) * 16 + 4 * q;
    float av[4], bv2[4];
#pragma unroll
    for (int i = 0; i < 4; ++i) { av[i] = alpha[o0 + i]; bv2[i] = beta[o0 + i]; }
#pragma unroll
    for (int nt = 0; nt < 4; ++nt) {
      const int wv = nt * 16 + t16;
#pragma unroll
      for (int i = 0; i < 4; ++i) {
        float v = acc[nt][mm][i] * av[i] + bv2[i];
        float sg = v / (1.f + __expf(-v));
        acc[nt][mm][i] = sg;
        if (o0 < C1)
          out[(((size_t)(b * 256 + chan_off + o0 + i)) * 64 + h) * 64 + wv] = sg;
      }
    }
  }
  if (HASPAD) {
    __syncthreads();                     // full sync: xs dead -> reuse as ep
#pragma unroll
    for (int mm = 0; mm < MM; ++mm) {
      const int o0 = (mt0 + mm) * 16 + 4 * q;
      if (o0 >= C1) {
#pragma unroll
        for (int nt = 0; nt < 4; ++nt) {
          const int px = rw * 64 + nt * 16 + t16;
          union { bf16 h4[4]; uint2 u; } pk;
#pragma unroll
          for (int i = 0; i < 4; ++i) pk.h4[i] = (bf16)acc[nt][mm][i];
          *(uint2*)&sm.ep[px * 72 + (o0 - C1)] = pk.u;
        }
      }
    }
    __syncthreads();
#pragma unroll
    for (int p = 0; p < 2; ++p) {
      int id = tid + p * 1024;           // 2048 chunks = 256 px x 8
      int c8 = id & 7, px = id >> 3;
      bf16x8 v = *(const bf16x8*)&sm.ep[px * 72 + c8 * 8];
      const int r = px >> 6, wv2 = px & 63;
      *(bf16x8*)&padout[(((size_t)(b * 64 + h0 + r)) * 64 + wv2) * 64 + c8 * 8] = v;
    }
  }
}

extern "C" void kernel_launch(void* const* d_in, const int* in_sizes, int n_in,
                              void* d_out, int out_size, void* d_ws, size_t ws_size,
                              hipStream_t stream) {
  QArgs qa;
  const float* x = (const float*)d_in[0];
  for (int L = 0; L < 5; ++L) {
    qa.w[L]  = (const float*)d_in[1 + 5 * L];
    qa.g[L]  = (const float*)d_in[2 + 5 * L];
    qa.bb[L] = (const float*)d_in[3 + 5 * L];
    qa.m[L]  = (const float*)d_in[4 + 5 * L];
    qa.v[L]  = (const float*)d_in[5 + 5 * L];
  }
  char* p = (char*)d_ws;
  bf16* wpk1 = (bf16*)p; p += (size_t)192 * 2304 * 2;
  bf16* wpk2 = (bf16*)p; p += (size_t)128 * 576 * 2;
  bf16* wpk3 = (bf16*)p; p += (size_t)64 * 576 * 2;
  float* a1 = (float*)p; p += 1024;
  float* b1 = (float*)p; p += 1024;
  float* a2 = (float*)p; p += 1024;
  float* b2 = (float*)p; p += 1024;
  float* a3 = (float*)p; p += 1024;
  float* b3 = (float*)p; p += 1024;
  float* zp = (float*)p; p += 128;                             // 128B zero page
  bf16* xT   = (bf16*)p; p += (size_t)32 * 64 * 64 * 256 * 2;  // 67.1 MB
  bf16* stem = (bf16*)p; p += (size_t)32 * 64 * 64 * 64 * 2;   // 16.8 MB
  bf16* tbuf = xT;                                             // alias: xT dead after stage 1
  qa.wpk[0] = wpk1; qa.wpk[1] = wpk2; qa.wpk[2] = wpk3;
  qa.alpha[0] = a1; qa.alpha[1] = a2; qa.alpha[2] = a3;
  qa.beta[0]  = b1; qa.beta[1]  = b2; qa.beta[2]  = b3;

  quant_kernel<<<384, 256, 0, stream>>>(qa);
  transpose_k<<<32 * 64 * 4, 256, 0, stream>>>(x, xT, zp);

  const bf16* zpb = (const bf16*)zp;
  conv_k<256, 12, 3, 128, true ><<<512, 1024, 0, stream>>>(xT,   wpk1, a1, b1, (float*)d_out, 0,   stem, zpb);
  conv_k< 64,  8, 2,  64, true ><<<512, 1024, 0, stream>>>(stem, wpk2, a2, b2, (float*)d_out, 128, tbuf, zpb);
  conv_k< 64,  4, 1,  64, false><<<512, 1024, 0, stream>>>(tbuf, wpk3, a3, b3, (float*)d_out, 192, nullptr, zpb);
}

// Round 6
// 435.163 us; speedup vs baseline: 1.0116x; 1.0116x over previous
//
#include <hip/hip_runtime.h>
#include <stdint.h>

#define EPSF 1e-5f

typedef __bf16 bf16;
typedef __attribute__((ext_vector_type(8))) __bf16 bf16x8;
typedef __attribute__((ext_vector_type(4))) float f32x4;

// async global->LDS, 16B per lane, dest = wave-uniform base + lane*16 (linear)
#define GL16(src, dst) __builtin_amdgcn_global_load_lds( \
    (const __attribute__((address_space(1))) void*)(src), \
    (__attribute__((address_space(3))) void*)(dst), 16, 0, 0)
// IR+ISA ordering fence for memory ops (pins GL16 issue order vs A-loads/ds_reads)
#define MEMFENCE() asm volatile("" ::: "memory")

// counted vmcnt: N = 2*MM keeps the 2-deep A-frag prefetch in flight while forcing
// all older ops (the GL16 staging DMAs, issued first) retired. Tight + sound.
template<int N> __device__ __forceinline__ void vwait() {
  static_assert(N == 2 || N == 4 || N == 6, "unsupported vmcnt");
  if constexpr (N == 2) asm volatile("s_waitcnt vmcnt(2)" ::: "memory");
  else if constexpr (N == 4) asm volatile("s_waitcnt vmcnt(4)" ::: "memory");
  else asm volatile("s_waitcnt vmcnt(6)" ::: "memory");
}

// ---------------- quantization + BN-fold + MFMA-fragment prepack -----------------
// Median via bitwise order-statistic binary search (MSB->LSB), packed 16|16 ranks.
struct QArgs {
  const float* w[5];
  const float* g[5];
  const float* bb[5];
  const float* m[5];
  const float* v[5];
  bf16* wpk[3];
  float* alpha[3];
  float* beta[3];
};

__global__ __launch_bounds__(256)
void quant_kernel(QArgs qa) {
  __shared__ int red[2][4];
  const int tid = threadIdx.x;
  const int blk = blockIdx.x;
  int layer, o;
  if (blk < 128)      { layer = 0; o = blk; }
  else if (blk < 192) { layer = 1; o = blk - 128; }
  else if (blk < 256) { layer = 2; o = blk - 192; }
  else if (blk < 320) { layer = 3; o = blk - 256; }
  else                { layer = 4; o = blk - 320; }
  const int I_[5]     = {256, 256, 64, 64, 64};
  const int gemm_[5]  = {0, 0, 1, 1, 2};
  const int obase_[5] = {0, 128, 0, 64, 0};
  const int gNMT[3]   = {12, 8, 4};
  const int I = I_[layer];
  const int n = I * 9;                       // 2304 or 576
  const float* w = qa.w[layer] + (size_t)o * n;

  unsigned key[9];
#pragma unroll
  for (int j = 0; j < 9; ++j) key[j] = 0xFFFFFFFFu;   // pad: never < cand
  {
    int c2 = 0;
    for (int i = tid; i < n; i += 256) key[c2++] = __float_as_uint(fabsf(w[i]));
  }

  const int wv = tid >> 6;
  unsigned pfx[2] = {0u, 0u};
  const int rank0 = n / 2 - 1, rank1 = n / 2;
  int pp = 0;
  for (int bit = 31; bit >= 0; --bit) {
    const unsigned c0 = pfx[0] | (1u << bit);
    const unsigned c1 = pfx[1] | (1u << bit);
    int loc = 0;
#pragma unroll
    for (int j = 0; j < 9; ++j)
      loc += (key[j] < c0 ? 1 : 0) + (key[j] < c1 ? 0x10000 : 0);
    loc += __shfl_xor(loc, 32); loc += __shfl_xor(loc, 16);
    loc += __shfl_xor(loc, 8);  loc += __shfl_xor(loc, 4);
    loc += __shfl_xor(loc, 2);  loc += __shfl_xor(loc, 1);
    if ((tid & 63) == 0) red[pp][wv] = loc;
    __syncthreads();
    const int tot = red[pp][0] + red[pp][1] + red[pp][2] + red[pp][3];
    if ((tot & 0xFFFF) <= rank0) pfx[0] = c0;
    if ((tot >> 16)    <= rank1) pfx[1] = c1;
    pp ^= 1;
  }
  const float s =
      fmaxf(0.5f * (__uint_as_float(pfx[0]) + __uint_as_float(pfx[1])), EPSF);

  const int g  = gemm_[layer];
  const int ob = obase_[layer];
  const int NMT = gNMT[g];
  if (tid == 0) {
    float inv = qa.g[layer][o] / sqrtf(qa.v[layer][o] + EPSF);
    qa.alpha[g][ob + o] = s * inv;
    qa.beta[g][ob + o]  = qa.bb[layer][o] - qa.m[layer][o] * inv;
  }
  const int og  = ob + o;
  const int mt  = og >> 4;
  const int l16 = og & 15;
  bf16* wp = qa.wpk[g];
  for (int i = tid; i < n; i += 256) {
    float t = rintf(w[i] / s);
    t = fmaxf(-1.f, fminf(1.f, t));
    int c = i / 9, pos = i % 9;
    int k = pos * I + c;
    int ks = k >> 5, kq = (k >> 3) & 3, jj = k & 7;
    wp[((size_t)((ks * NMT + mt) * 64 + kq * 16 + l16)) * 8 + jj] = (bf16)t;
  }
}

// ---------------- NCHW fp32 -> c-minor bf16 transpose: xT[b][h][w][256] ----------
// float4 global loads (4x fewer VMEM instrs), float2 LDS reads on output side.
__global__ __launch_bounds__(256)
void transpose_k(const float* __restrict__ x, bf16* __restrict__ xT,
                 float* __restrict__ zp) {
  if (blockIdx.x == 0 && threadIdx.x < 32) zp[threadIdx.x] = 0.0f;  // 128B zero page
  __shared__ float tile[64 * 66];
  const int tid = threadIdx.x;
  const int blk = blockIdx.x;
  const int cg = blk & 3;
  const int h  = (blk >> 2) & 63;
  const int b  = blk >> 8;
  const int w4 = (tid & 15) * 4;
  const int cb = tid >> 4;               // 0..15
#pragma unroll
  for (int p = 0; p < 4; ++p) {
    int c = cb + p * 16;
    const float4 v =
        *(const float4*)&x[(((size_t)(b * 256 + cg * 64 + c)) * 64 + h) * 64 + w4];
    tile[(w4 + 0) * 66 + c] = v.x;
    tile[(w4 + 1) * 66 + c] = v.y;
    tile[(w4 + 2) * 66 + c] = v.z;
    tile[(w4 + 3) * 66 + c] = v.w;
  }
  __syncthreads();
#pragma unroll
  for (int p = 0; p < 2; ++p) {
    int id = tid + p * 256;
    int c8 = id & 7, w2 = id >> 3;
    const float* src = &tile[w2 * 66 + c8 * 8];
    float2 f0 = *(const float2*)(src + 0);
    float2 f1 = *(const float2*)(src + 2);
    float2 f2 = *(const float2*)(src + 4);
    float2 f3 = *(const float2*)(src + 6);
    bf16x8 v;
    v[0] = (bf16)f0.x; v[1] = (bf16)f0.y; v[2] = (bf16)f1.x; v[3] = (bf16)f1.y;
    v[4] = (bf16)f2.x; v[5] = (bf16)f2.y; v[6] = (bf16)f3.x; v[7] = (bf16)f3.y;
    *(bf16x8*)&xT[(((size_t)(b * 64 + h)) * 64 + w2) * 256 + cg * 64 + c8 * 8] = v;
  }
}

// ---------------- implicit-GEMM conv3x3 (pad=1) + fused BN + SiLU ----------------
// Template over (TPB, RB): block = RB rows x 64 w x NMT*16 ch, TPB/64 waves,
// NG = NMT/MM m-groups, rw = wave/NG, mt0 = (wave%NG)*MM.
//   conv1: TPB=512, RB=2 (2 blocks/CU -> barrier overlap partner; measured best)
//   conv2: TPB=1024, RB=4 (amortizes epilogue; measured best at R5)
//   conv3: TPB=512, RB=4 (4-row amortization + 2 blocks/CU, fully resident grid)
// Staging: global_load_lds width=16, linear LDS, chunk XOR-swizzle on global
// source + read side (G21). Counted vmcnt(2*MM): all GL16s (older) retired, the
// 2-deep A-frag ring (newest 2*MM loads) stays in flight. setprio(1) over MFMA.
// NC==2: both c-chunks staged in prologue via step[] (pad-safe), ONE barrier.
template<int CIN, int NMT, int MM, int C1, bool HASPAD, int TPB, int RB, bool XSWZ>
__global__ __launch_bounds__(TPB, 4)
void conv_k(const bf16* __restrict__ xin,   // [B][64][64][CIN] c-minor bf16
            const bf16* __restrict__ wpk,
            const float* __restrict__ alpha,
            const float* __restrict__ beta,
            float* __restrict__ out, int chan_off,
            bf16* __restrict__ padout,      // [B][64][64][64] c-minor bf16
            const bf16* __restrict__ zpage) {
  constexpr int NC    = CIN / 32;
  constexpr int NG    = NMT / MM;          // m-groups per row
  constexpr int RS    = RB + 2;            // staged rows incl. halo
  constexpr int NCHK  = RS * 66 * 4;       // live 16B chunks per buffer
  constexpr int SLOTS = (RB == 2) ? 1088 : 1600;  // +guard (wave-granular GL16)
  constexpr int BUFB  = SLOTS * 16;        // buffer stride, bytes
  constexpr int P     = (NCHK + TPB - 1) / TPB;   // staging passes
  constexpr int HT    = 64 / RB;           // h-tiles per image
  constexpr int NBLK  = 32 * HT;

  __shared__ __align__(16) union U {
    bf16 xs[2][SLOTS * 8];
    bf16 ep[RB * 64 * 72];
  } sm;

  const int tid  = threadIdx.x;
  const int wave = tid >> 6;
  const int lane = tid & 63;
  const int q    = lane >> 4;
  const int t16  = lane & 15;
  const int rw   = wave / NG;              // output row within block
  const int mt0  = (wave % NG) * MM;
  const int wg   = (int)blockIdx.x;
  const int wgid = XSWZ ? (wg & 7) * (NBLK / 8) + (wg >> 3) : wg;
  const int b    = wgid / HT;
  const int h0   = (wgid % HT) * RB;

  // staging map: chunk id = (r*66 + j)*4 + c8p ; per-pass ids = tid + p*TPB
  const bf16* srcp[P];
  int step[P];
#pragma unroll
  for (int p = 0; p < P; ++p) {
    const int id = tid + p * TPB;
    const int c8p = id & 3, rj = id >> 2;
    const int j = rj % 66, r = rj / 66;
    const int hh = h0 + r - 1, ww = j - 1;
    const bool v = (id < NCHK) && ((unsigned)hh < 64u) && ((unsigned)ww < 64u);
    const int c8 = c8p ^ ((j >> 1) & 3);          // inverse swizzle on source
    srcp[p] = v ? &xin[(((size_t)(b * 64 + hh)) * 64 + ww) * CIN + c8 * 8] : zpage;
    step[p] = v ? 32 : 0;                          // +32 ch per c-iter, pad lanes pinned
  }

  auto stage = [&](char* base, bool second) {
#pragma unroll
    for (int p = 0; p < P; ++p) {
      if ((p + 1) * TPB <= NCHK || p * TPB + wave * 64 < NCHK)
        GL16(srcp[p] + (second ? step[p] : 0), base + (p * TPB + wave * 64) * 16);
    }
  };

  // B-read base addresses (buf0), one per kw
  int Caddr[3];
#pragma unroll
  for (int kw = 0; kw < 3; ++kw) {
    const int col = t16 + kw;
    Caddr[kw] = rw * 4224 + col * 64 + ((q ^ ((col >> 1) & 3)) << 4);
  }

  char* const lds0 = (char*)&sm.xs[0][0];

  // prologue staging
  stage(lds0, false);
  if constexpr (NC == 2) {
    stage(lds0 + BUFB, true);              // second 32-ch chunk, pad-safe via step
  } else {
#pragma unroll
    for (int p = 0; p < P; ++p) srcp[p] += step[p];
  }
  MEMFENCE();

  // A-fragment ring, 2 taps deep: fr[t%3] holds tap t
  bf16x8 fr[3][MM];
#pragma unroll
  for (int mm = 0; mm < MM; ++mm) {
    fr[0][mm] = *(const bf16x8*)&wpk[((size_t)(mt0 + mm) * 64 + lane) * 8];
    fr[1][mm] = *(const bf16x8*)&wpk[((size_t)(NC * NMT + mt0 + mm) * 64 + lane) * 8];
  }

  f32x4 acc[4][MM] = {};
  int tog = BUFB;

  for (int ci = 0; ci < NC; ++ci) {
    if (NC > 2 || ci == 0) {
      vwait<2 * MM>();                     // GL16s retired; A-frag ring stays in flight
      __builtin_amdgcn_s_barrier();
    }
    if constexpr (NC > 2) {
      if (ci + 1 < NC) {                   // issue next chunk's direct-to-LDS loads now
        stage(lds0 + (((ci + 1) & 1) ? BUFB : 0), false);
#pragma unroll
        for (int p = 0; p < P; ++p) srcp[p] += step[p];
      }
    }
    MEMFENCE();                            // GL16 issue pinned before A-loads/ds_reads
    __builtin_amdgcn_s_setprio(1);
#pragma unroll
    for (int pos = 0; pos < 9; ++pos) {
      const int t = pos + 2;               // prefetch 2 taps ahead into fr[t%3]
      if (t <= 8) {
        const int ksn = t * NC + ci;
#pragma unroll
        for (int mm = 0; mm < MM; ++mm)
          fr[t % 3][mm] = *(const bf16x8*)&wpk[((size_t)(ksn * NMT + mt0 + mm) * 64 + lane) * 8];
      } else if (ci + 1 < NC) {            // next c-iter taps 0/1, fly across barrier
        const int ksn = (t - 9) * NC + (ci + 1);
#pragma unroll
        for (int mm = 0; mm < MM; ++mm)
          fr[t % 3][mm] = *(const bf16x8*)&wpk[((size_t)(ksn * NMT + mt0 + mm) * 64 + lane) * 8];
      }
      const int kh = pos / 3, kw = pos % 3;
#pragma unroll
      for (int nt = 0; nt < 4; ++nt) {
        const bf16x8 bv =
            *(const bf16x8*)(lds0 + (Caddr[kw] + nt * 1024 + kh * 4224));
#pragma unroll
        for (int mm = 0; mm < MM; ++mm)
          acc[nt][mm] = __builtin_amdgcn_mfma_f32_16x16x32_bf16(fr[pos % 3][mm], bv, acc[nt][mm], 0, 0, 0);
      }
    }
    __builtin_amdgcn_s_setprio(0);
#pragma unroll
    for (int kw = 0; kw < 3; ++kw) Caddr[kw] += tog;   // buffer toggle
    tog = -tog;
  }

  // epilogue: BN + SiLU; fp32 NCHW stores for o < C1
  const int h = h0 + rw;
#pragma unroll
  for (int mm = 0; mm < MM; ++mm) {
    const int o0 = (mt0 + mm) * 16 + 4 * q;
    float av[4], bv2[4];
#pragma unroll
    for (int i = 0; i < 4; ++i) { av[i] = alpha[o0 + i]; bv2[i] = beta[o0 + i]; }
#pragma unroll
    for (int nt = 0; nt < 4; ++nt) {
      const int wv = nt * 16 + t16;
#pragma unroll
      for (int i = 0; i < 4; ++i) {
        float v = acc[nt][mm][i] * av[i] + bv2[i];
        float sg = v / (1.f + __expf(-v));
        acc[nt][mm][i] = sg;
        if (o0 < C1)
          out[(((size_t)(b * 256 + chan_off + o0 + i)) * 64 + h) * 64 + wv] = sg;
      }
    }
  }
  if (HASPAD) {
    __syncthreads();                       // full sync: xs dead -> reuse as ep
#pragma unroll
    for (int mm = 0; mm < MM; ++mm) {
      const int o0 = (mt0 + mm) * 16 + 4 * q;
      if (o0 >= C1) {
#pragma unroll
        for (int nt = 0; nt < 4; ++nt) {
          const int px = rw * 64 + nt * 16 + t16;
          union { bf16 h4[4]; uint2 u; } pk;
#pragma unroll
          for (int i = 0; i < 4; ++i) pk.h4[i] = (bf16)acc[nt][mm][i];
          *(uint2*)&sm.ep[px * 72 + (o0 - C1)] = pk.u;
        }
      }
    }
    __syncthreads();
    constexpr int EPP = (RB * 64 * 8) / TPB;
#pragma unroll
    for (int p = 0; p < EPP; ++p) {
      int id = tid + p * TPB;              // RB*64*8 chunks = RB*64 px x 8
      int c8 = id & 7, px = id >> 3;
      bf16x8 v = *(const bf16x8*)&sm.ep[px * 72 + c8 * 8];
      const int r = px >> 6, wv2 = px & 63;
      *(bf16x8*)&padout[(((size_t)(b * 64 + h0 + r)) * 64 + wv2) * 64 + c8 * 8] = v;
    }
  }
}

extern "C" void kernel_launch(void* const* d_in, const int* in_sizes, int n_in,
                              void* d_out, int out_size, void* d_ws, size_t ws_size,
                              hipStream_t stream) {
  QArgs qa;
  const float* x = (const float*)d_in[0];
  for (int L = 0; L < 5; ++L) {
    qa.w[L]  = (const float*)d_in[1 + 5 * L];
    qa.g[L]  = (const float*)d_in[2 + 5 * L];
    qa.bb[L] = (const float*)d_in[3 + 5 * L];
    qa.m[L]  = (const float*)d_in[4 + 5 * L];
    qa.v[L]  = (const float*)d_in[5 + 5 * L];
  }
  char* p = (char*)d_ws;
  bf16* wpk1 = (bf16*)p; p += (size_t)192 * 2304 * 2;
  bf16* wpk2 = (bf16*)p; p += (size_t)128 * 576 * 2;
  bf16* wpk3 = (bf16*)p; p += (size_t)64 * 576 * 2;
  float* a1 = (float*)p; p += 1024;
  float* b1 = (float*)p; p += 1024;
  float* a2 = (float*)p; p += 1024;
  float* b2 = (float*)p; p += 1024;
  float* a3 = (float*)p; p += 1024;
  float* b3 = (float*)p; p += 1024;
  float* zp = (float*)p; p += 128;                             // 128B zero page
  bf16* xT   = (bf16*)p; p += (size_t)32 * 64 * 64 * 256 * 2;  // 67.1 MB
  bf16* stem = (bf16*)p; p += (size_t)32 * 64 * 64 * 64 * 2;   // 16.8 MB
  bf16* tbuf = xT;                                             // alias: xT dead after stage 1
  qa.wpk[0] = wpk1; qa.wpk[1] = wpk2; qa.wpk[2] = wpk3;
  qa.alpha[0] = a1; qa.alpha[1] = a2; qa.alpha[2] = a3;
  qa.beta[0]  = b1; qa.beta[1]  = b2; qa.beta[2]  = b3;

  quant_kernel<<<384, 256, 0, stream>>>(qa);
  transpose_k<<<32 * 64 * 4, 256, 0, stream>>>(x, xT, zp);

  const bf16* zpb = (const bf16*)zp;
  conv_k<256, 12, 3, 128, true,  512, 2, false><<<1024,  512, 0, stream>>>(xT,   wpk1, a1, b1, (float*)d_out, 0,   stem, zpb);
  conv_k< 64,  8, 2,  64, true, 1024, 4, true ><<< 512, 1024, 0, stream>>>(stem, wpk2, a2, b2, (float*)d_out, 128, tbuf, zpb);
  conv_k< 64,  4, 2,  64, false, 512, 4, true ><<< 512,  512, 0, stream>>>(tbuf, wpk3, a3, b3, (float*)d_out, 192, nullptr, zpb);
}

// Round 8
// 417.653 us; speedup vs baseline: 1.0540x; 1.0419x over previous
//
#include <hip/hip_runtime.h>
#include <stdint.h>

#define EPSF 1e-5f

typedef __bf16 bf16;
typedef __attribute__((ext_vector_type(8))) __bf16 bf16x8;
typedef __attribute__((ext_vector_type(4))) float f32x4;

// async global->LDS, 16B per lane, dest = wave-uniform base + lane*16 (linear)
#define GL16(src, dst) __builtin_amdgcn_global_load_lds( \
    (const __attribute__((address_space(1))) void*)(src), \
    (__attribute__((address_space(3))) void*)(dst), 16, 0, 0)
// IR+ISA ordering fence for memory ops (pins GL16 issue order vs A-loads/ds_reads)
#define MEMFENCE() asm volatile("" ::: "memory")

// counted vmcnt. Ledger per wait site (re-derived R7 after the ci=0 no-op bug):
//  - ci==0 (all NC): outstanding = GL16s + MM aE-loads -> vwait<MM> retires ALL
//    GL16s (both buffers for NC==2), keeps aE in flight.
//  - ci>=1 (NC>2): newest 2*MM = pos7 tap8-loads + pos8 next-tap0-loads; vmcnt(2*MM)
//    retires everything older incl. chunk ci's GL16s (issued at top of iter ci-1).
template<int N> __device__ __forceinline__ void vwait() {
  static_assert(N == 2 || N == 3 || N == 4 || N == 6, "unsupported vmcnt");
  if constexpr (N == 2) asm volatile("s_waitcnt vmcnt(2)" ::: "memory");
  else if constexpr (N == 3) asm volatile("s_waitcnt vmcnt(3)" ::: "memory");
  else if constexpr (N == 4) asm volatile("s_waitcnt vmcnt(4)" ::: "memory");
  else asm volatile("s_waitcnt vmcnt(6)" ::: "memory");
}

// ---------------- fused prep: quant (blocks 0..383) + transpose (384..8575) -----
// quant: median via bitwise order-statistic binary search (MSB->LSB), packed
// 16|16 ranks; BN-fold; MFMA A-fragment prepack. transpose: NCHW fp32 -> c-minor
// bf16 xT[b][h][w][256], float4 global loads, float2 LDS reads.
struct QArgs {
  const float* w[5];
  const float* g[5];
  const float* bb[5];
  const float* m[5];
  const float* v[5];
  bf16* wpk[3];
  float* alpha[3];
  float* beta[3];
};

__global__ __launch_bounds__(256)
void prep_k(QArgs qa, const float* __restrict__ x, bf16* __restrict__ xT,
            float* __restrict__ zp) {
  __shared__ int red[2][4];
  __shared__ float tile[64 * 66];
  const int tid = threadIdx.x;
  if (blockIdx.x == 0 && tid < 32) zp[tid] = 0.0f;   // 128B zero page

  if (blockIdx.x < 384) {
    // ---------------- quant branch ----------------
    const int blk = blockIdx.x;
    int layer, o;
    if (blk < 128)      { layer = 0; o = blk; }
    else if (blk < 192) { layer = 1; o = blk - 128; }
    else if (blk < 256) { layer = 2; o = blk - 192; }
    else if (blk < 320) { layer = 3; o = blk - 256; }
    else                { layer = 4; o = blk - 320; }
    const int I_[5]     = {256, 256, 64, 64, 64};
    const int gemm_[5]  = {0, 0, 1, 1, 2};
    const int obase_[5] = {0, 128, 0, 64, 0};
    const int gNMT[3]   = {12, 8, 4};
    const int I = I_[layer];
    const int n = I * 9;                       // 2304 or 576
    const float* w = qa.w[layer] + (size_t)o * n;

    unsigned key[9];
#pragma unroll
    for (int j = 0; j < 9; ++j) key[j] = 0xFFFFFFFFu;   // pad: never < cand
    {
      int c2 = 0;
      for (int i = tid; i < n; i += 256) key[c2++] = __float_as_uint(fabsf(w[i]));
    }

    const int wv = tid >> 6;
    unsigned pfx[2] = {0u, 0u};
    const int rank0 = n / 2 - 1, rank1 = n / 2;
    int pp = 0;
    for (int bit = 31; bit >= 0; --bit) {
      const unsigned c0 = pfx[0] | (1u << bit);
      const unsigned c1 = pfx[1] | (1u << bit);
      int loc = 0;
#pragma unroll
      for (int j = 0; j < 9; ++j)
        loc += (key[j] < c0 ? 1 : 0) + (key[j] < c1 ? 0x10000 : 0);
      loc += __shfl_xor(loc, 32); loc += __shfl_xor(loc, 16);
      loc += __shfl_xor(loc, 8);  loc += __shfl_xor(loc, 4);
      loc += __shfl_xor(loc, 2);  loc += __shfl_xor(loc, 1);
      if ((tid & 63) == 0) red[pp][wv] = loc;
      __syncthreads();
      const int tot = red[pp][0] + red[pp][1] + red[pp][2] + red[pp][3];
      if ((tot & 0xFFFF) <= rank0) pfx[0] = c0;
      if ((tot >> 16)    <= rank1) pfx[1] = c1;
      pp ^= 1;
    }
    const float s =
        fmaxf(0.5f * (__uint_as_float(pfx[0]) + __uint_as_float(pfx[1])), EPSF);

    const int g  = gemm_[layer];
    const int ob = obase_[layer];
    const int NMT = gNMT[g];
    if (tid == 0) {
      float inv = qa.g[layer][o] / sqrtf(qa.v[layer][o] + EPSF);
      qa.alpha[g][ob + o] = s * inv;
      qa.beta[g][ob + o]  = qa.bb[layer][o] - qa.m[layer][o] * inv;
    }
    const int og  = ob + o;
    const int mt  = og >> 4;
    const int l16 = og & 15;
    bf16* wp = qa.wpk[g];
    for (int i = tid; i < n; i += 256) {
      float t = rintf(w[i] / s);
      t = fmaxf(-1.f, fminf(1.f, t));
      int c = i / 9, pos = i % 9;
      int k = pos * I + c;
      int ks = k >> 5, kq = (k >> 3) & 3, jj = k & 7;
      wp[((size_t)((ks * NMT + mt) * 64 + kq * 16 + l16)) * 8 + jj] = (bf16)t;
    }
    return;
  }

  // ---------------- transpose branch ----------------
  const int blk = blockIdx.x - 384;
  const int cg = blk & 3;
  const int h  = (blk >> 2) & 63;
  const int b  = blk >> 8;
  const int w4 = (tid & 15) * 4;
  const int cb = tid >> 4;               // 0..15
#pragma unroll
  for (int p = 0; p < 4; ++p) {
    int c = cb + p * 16;
    const float4 v =
        *(const float4*)&x[(((size_t)(b * 256 + cg * 64 + c)) * 64 + h) * 64 + w4];
    tile[(w4 + 0) * 66 + c] = v.x;
    tile[(w4 + 1) * 66 + c] = v.y;
    tile[(w4 + 2) * 66 + c] = v.z;
    tile[(w4 + 3) * 66 + c] = v.w;
  }
  __syncthreads();
#pragma unroll
  for (int p = 0; p < 2; ++p) {
    int id = tid + p * 256;
    int c8 = id & 7, w2 = id >> 3;
    const float* src = &tile[w2 * 66 + c8 * 8];
    float2 f0 = *(const float2*)(src + 0);
    float2 f1 = *(const float2*)(src + 2);
    float2 f2 = *(const float2*)(src + 4);
    float2 f3 = *(const float2*)(src + 6);
    bf16x8 v;
    v[0] = (bf16)f0.x; v[1] = (bf16)f0.y; v[2] = (bf16)f1.x; v[3] = (bf16)f1.y;
    v[4] = (bf16)f2.x; v[5] = (bf16)f2.y; v[6] = (bf16)f3.x; v[7] = (bf16)f3.y;
    *(bf16x8*)&xT[(((size_t)(b * 64 + h)) * 64 + w2) * 256 + cg * 64 + c8 * 8] = v;
  }
}

// ---------------- implicit-GEMM conv3x3 (pad=1) + fused BN + SiLU ----------------
// Template over (TPB, RB): block = RB rows x 64 w x NMT*16 ch, TPB/64 waves.
// B-fragments double-buffer one tap ahead in registers (issue tap t+1's 4
// ds_reads, then run tap t's MFMAs) so the LDS pipe fills under the MFMA pipe.
// A-fragments: 2-slot ping-pong; next c-iter tap0 load is AFTER the pos==8 MFMAs
// (R7 WAR bugfix: it overwrites aE which pos==8 consumes). Staging:
// global_load_lds w=16, linear LDS, chunk XOR-swizzle on global source + read
// side (G21). vmcnt ledgers: see vwait comment (R7 ci=0 no-op bugfix).
template<int CIN, int NMT, int MM, int C1, bool HASPAD, int TPB, int RB, bool XSWZ>
__global__ __launch_bounds__(TPB, 4)
void conv_k(const bf16* __restrict__ xin,   // [B][64][64][CIN] c-minor bf16
            const bf16* __restrict__ wpk,
            const float* __restrict__ alpha,
            const float* __restrict__ beta,
            float* __restrict__ out, int chan_off,
            bf16* __restrict__ padout,      // [B][64][64][64] c-minor bf16
            const bf16* __restrict__ zpage) {
  constexpr int NC    = CIN / 32;
  constexpr int NG    = NMT / MM;          // m-groups per row
  constexpr int RS    = RB + 2;            // staged rows incl. halo
  constexpr int NCHK  = RS * 66 * 4;       // live 16B chunks per buffer
  constexpr int SLOTS = (RB == 2) ? 1088 : 1600;  // +guard (wave-granular GL16)
  constexpr int BUFB  = SLOTS * 16;        // buffer stride, bytes
  constexpr int P     = (NCHK + TPB - 1) / TPB;   // staging passes
  constexpr int HT    = 64 / RB;           // h-tiles per image
  constexpr int NBLK  = 32 * HT;

  __shared__ __align__(16) union U {
    bf16 xs[2][SLOTS * 8];
    bf16 ep[RB * 64 * 72];
  } sm;

  const int tid  = threadIdx.x;
  const int wave = tid >> 6;
  const int lane = tid & 63;
  const int q    = lane >> 4;
  const int t16  = lane & 15;
  const int rw   = wave / NG;              // output row within block
  const int mt0  = (wave % NG) * MM;
  const int wg   = (int)blockIdx.x;
  const int wgid = XSWZ ? (wg & 7) * (NBLK / 8) + (wg >> 3) : wg;
  const int b    = wgid / HT;
  const int h0   = (wgid % HT) * RB;

  // staging map: chunk id = (r*66 + j)*4 + c8p ; per-pass ids = tid + p*TPB
  const bf16* srcp[P];
  int step[P];
#pragma unroll
  for (int p = 0; p < P; ++p) {
    const int id = tid + p * TPB;
    const int c8p = id & 3, rj = id >> 2;
    const int j = rj % 66, r = rj / 66;
    const int hh = h0 + r - 1, ww = j - 1;
    const bool v = (id < NCHK) && ((unsigned)hh < 64u) && ((unsigned)ww < 64u);
    const int c8 = c8p ^ ((j >> 1) & 3);          // inverse swizzle on source
    srcp[p] = v ? &xin[(((size_t)(b * 64 + hh)) * 64 + ww) * CIN + c8 * 8] : zpage;
    step[p] = v ? 32 : 0;                          // +32 ch per c-iter, pad lanes pinned
  }

  auto stage = [&](char* base, bool second) {
#pragma unroll
    for (int p = 0; p < P; ++p) {
      if ((p + 1) * TPB <= NCHK || p * TPB + wave * 64 < NCHK)
        GL16(srcp[p] + (second ? step[p] : 0), base + (p * TPB + wave * 64) * 16);
    }
  };

  // B-read base addresses (buf0), one per kw
  int Caddr[3];
#pragma unroll
  for (int kw = 0; kw < 3; ++kw) {
    const int col = t16 + kw;
    Caddr[kw] = rw * 4224 + col * 64 + ((q ^ ((col >> 1) & 3)) << 4);
  }

  char* const lds0 = (char*)&sm.xs[0][0];

  // prologue staging
  stage(lds0, false);
  if constexpr (NC == 2) {
    stage(lds0 + BUFB, true);              // second 32-ch chunk, pad-safe via step
  } else {
#pragma unroll
    for (int p = 0; p < P; ++p) srcp[p] += step[p];
  }
  MEMFENCE();

  // A-fragment 2-slot ping-pong: aE = tap0
  bf16x8 aE[MM], aO[MM];
#pragma unroll
  for (int mm = 0; mm < MM; ++mm)
    aE[mm] = *(const bf16x8*)&wpk[((size_t)(mt0 + mm) * 64 + lane) * 8];

  f32x4 acc[4][MM] = {};
  int tog = BUFB;

  for (int ci = 0; ci < NC; ++ci) {
    if (ci == 0) {
      vwait<MM>();                         // ALL GL16s retired; aE stays in flight
      __builtin_amdgcn_s_barrier();
    } else if constexpr (NC > 2) {
      vwait<2 * MM>();                     // GL16s retired; tap8+next-tap0 in flight
      __builtin_amdgcn_s_barrier();
    }
    if constexpr (NC > 2) {
      if (ci + 1 < NC) {                   // issue next chunk's direct-to-LDS loads
        stage(lds0 + (((ci + 1) & 1) ? BUFB : 0), false);
#pragma unroll
        for (int p = 0; p < P; ++p) srcp[p] += step[p];
      }
    }
    MEMFENCE();                            // GL16 issue pinned before A/B reads
    // B-fragment double buffer: pre-read tap0
    bf16x8 bb0[4], bb1[4];
#pragma unroll
    for (int nt = 0; nt < 4; ++nt)
      bb0[nt] = *(const bf16x8*)(lds0 + (Caddr[0] + nt * 1024));
    __builtin_amdgcn_s_setprio(1);
#pragma unroll
    for (int pos = 0; pos < 9; ++pos) {
      bf16x8* bc = (pos & 1) ? bb1 : bb0;
      bf16x8* bn = (pos & 1) ? bb0 : bb1;
      if (pos < 8) {                       // issue tap pos+1 B-reads first
        const int kh1 = (pos + 1) / 3, kw1 = (pos + 1) % 3;
#pragma unroll
        for (int nt = 0; nt < 4; ++nt)
          bn[nt] = *(const bf16x8*)(lds0 + (Caddr[kw1] + nt * 1024 + kh1 * 4224));
      }
      bf16x8* ac = (pos & 1) ? aO : aE;
      bf16x8* an = (pos & 1) ? aE : aO;
      if (pos < 8) {                       // A prefetch one tap ahead
        const int ksn = (pos + 1) * NC + ci;
#pragma unroll
        for (int mm = 0; mm < MM; ++mm)
          an[mm] = *(const bf16x8*)&wpk[((size_t)(ksn * NMT + mt0 + mm) * 64 + lane) * 8];
      }
#pragma unroll
      for (int nt = 0; nt < 4; ++nt)
#pragma unroll
        for (int mm = 0; mm < MM; ++mm)
          acc[nt][mm] = __builtin_amdgcn_mfma_f32_16x16x32_bf16(ac[mm], bc[nt], acc[nt][mm], 0, 0, 0);
      if (pos == 8 && ci + 1 < NC) {       // next c-iter tap0 AFTER consuming aE
#pragma unroll
        for (int mm = 0; mm < MM; ++mm)
          aE[mm] = *(const bf16x8*)&wpk[((size_t)((ci + 1) * NMT + mt0 + mm) * 64 + lane) * 8];
      }
    }
    __builtin_amdgcn_s_setprio(0);
#pragma unroll
    for (int kw = 0; kw < 3; ++kw) Caddr[kw] += tog;   // buffer toggle
    tog = -tog;
  }

  // epilogue: BN + SiLU; fp32 NCHW stores for o < C1
  const int h = h0 + rw;
#pragma unroll
  for (int mm = 0; mm < MM; ++mm) {
    const int o0 = (mt0 + mm) * 16 + 4 * q;
    float av[4], bv2[4];
#pragma unroll
    for (int i = 0; i < 4; ++i) { av[i] = alpha[o0 + i]; bv2[i] = beta[o0 + i]; }
#pragma unroll
    for (int nt = 0; nt < 4; ++nt) {
      const int wv = nt * 16 + t16;
#pragma unroll
      for (int i = 0; i < 4; ++i) {
        float v = acc[nt][mm][i] * av[i] + bv2[i];
        float sg = v / (1.f + __expf(-v));
        acc[nt][mm][i] = sg;
        if (o0 < C1)
          out[(((size_t)(b * 256 + chan_off + o0 + i)) * 64 + h) * 64 + wv] = sg;
      }
    }
  }
  if (HASPAD) {
    __syncthreads();                       // full sync: xs dead -> reuse as ep
#pragma unroll
    for (int mm = 0; mm < MM; ++mm) {
      const int o0 = (mt0 + mm) * 16 + 4 * q;
      if (o0 >= C1) {
#pragma unroll
        for (int nt = 0; nt < 4; ++nt) {
          const int px = rw * 64 + nt * 16 + t16;
          union { bf16 h4[4]; uint2 u; } pk;
#pragma unroll
          for (int i = 0; i < 4; ++i) pk.h4[i] = (bf16)acc[nt][mm][i];
          *(uint2*)&sm.ep[px * 72 + (o0 - C1)] = pk.u;
        }
      }
    }
    __syncthreads();
    constexpr int EPP = (RB * 64 * 8) / TPB;
#pragma unroll
    for (int p = 0; p < EPP; ++p) {
      int id = tid + p * TPB;              // RB*64*8 chunks = RB*64 px x 8
      int c8 = id & 7, px = id >> 3;
      bf16x8 v = *(const bf16x8*)&sm.ep[px * 72 + c8 * 8];
      const int r = px >> 6, wv2 = px & 63;
      *(bf16x8*)&padout[(((size_t)(b * 64 + h0 + r)) * 64 + wv2) * 64 + c8 * 8] = v;
    }
  }
}

extern "C" void kernel_launch(void* const* d_in, const int* in_sizes, int n_in,
                              void* d_out, int out_size, void* d_ws, size_t ws_size,
                              hipStream_t stream) {
  QArgs qa;
  const float* x = (const float*)d_in[0];
  for (int L = 0; L < 5; ++L) {
    qa.w[L]  = (const float*)d_in[1 + 5 * L];
    qa.g[L]  = (const float*)d_in[2 + 5 * L];
    qa.bb[L] = (const float*)d_in[3 + 5 * L];
    qa.m[L]  = (const float*)d_in[4 + 5 * L];
    qa.v[L]  = (const float*)d_in[5 + 5 * L];
  }
  char* p = (char*)d_ws;
  bf16* wpk1 = (bf16*)p; p += (size_t)192 * 2304 * 2;
  bf16* wpk2 = (bf16*)p; p += (size_t)128 * 576 * 2;
  bf16* wpk3 = (bf16*)p; p += (size_t)64 * 576 * 2;
  float* a1 = (float*)p; p += 1024;
  float* b1 = (float*)p; p += 1024;
  float* a2 = (float*)p; p += 1024;
  float* b2 = (float*)p; p += 1024;
  float* a3 = (float*)p; p += 1024;
  float* b3 = (float*)p; p += 1024;
  float* zp = (float*)p; p += 128;                             // 128B zero page
  bf16* xT   = (bf16*)p; p += (size_t)32 * 64 * 64 * 256 * 2;  // 67.1 MB
  bf16* stem = (bf16*)p; p += (size_t)32 * 64 * 64 * 64 * 2;   // 16.8 MB
  bf16* tbuf = xT;                                             // alias: xT dead after stage 1
  qa.wpk[0] = wpk1; qa.wpk[1] = wpk2; qa.wpk[2] = wpk3;
  qa.alpha[0] = a1; qa.alpha[1] = a2; qa.alpha[2] = a3;
  qa.beta[0]  = b1; qa.beta[1]  = b2; qa.beta[2]  = b3;

  prep_k<<<384 + 32 * 64 * 4, 256, 0, stream>>>(qa, x, xT, zp);

  const bf16* zpb = (const bf16*)zp;
  conv_k<256, 12, 3, 128, true,  512, 2, false><<<1024,  512, 0, stream>>>(xT,   wpk1, a1, b1, (float*)d_out, 0,   stem, zpb);
  conv_k< 64,  8, 2,  64, true, 1024, 4, true ><<< 512, 1024, 0, stream>>>(stem, wpk2, a2, b2, (float*)d_out, 128, tbuf, zpb);
  conv_k< 64,  4, 2,  64, false, 512, 4, true ><<< 512,  512, 0, stream>>>(tbuf, wpk3, a3, b3, (float*)d_out, 192, nullptr, zpb);
}